// Round 1
// baseline (1124.318 us; speedup 1.0000x reference)
//
#include <hip/hip_runtime.h>
#include <math.h>

namespace {

constexpr int Nn = 8192;   // N
constexpr int Ss = 1024;   // S
constexpr int Kk = 32;     // K
constexpr float F_EPS = 1e-7f;
constexpr float F_BN_EPS = 1e-5f;

__global__ __launch_bounds__(256) void rcri_fused(
    const float* __restrict__ contour,
    const float* __restrict__ loa,
    const float* __restrict__ prev,
    const float* __restrict__ ew1, const float* __restrict__ eb1,
    const float* __restrict__ eg1, const float* __restrict__ ebeta1,
    const float* __restrict__ em1, const float* __restrict__ ev1,
    const float* __restrict__ ew2, const float* __restrict__ eb2,
    const float* __restrict__ eg2, const float* __restrict__ ebeta2,
    const float* __restrict__ em2, const float* __restrict__ ev2,
    const float* __restrict__ fw1, const float* __restrict__ fb1,
    const float* __restrict__ fg1, const float* __restrict__ fbeta1,
    const float* __restrict__ fm1, const float* __restrict__ fv1,
    const float* __restrict__ fw2, const float* __restrict__ fb2,
    const float* __restrict__ fg2, const float* __restrict__ fbeta2,
    const float* __restrict__ fm2, const float* __restrict__ fv2,
    float* __restrict__ out)
{
  __shared__ __align__(16) float rif[Kk][8];     // features per (k): [f4,d2,a1,a2,f3o,a4,a5,f7o]
  __shared__ __align__(16) float h1[Kk][36];     // conv1 out (32 ch), padded
  __shared__ __align__(16) float cat[Kk][132];   // conv2 out (0..63) + gathered prev (64..127), padded
  __shared__ __align__(16) float h3[Kk][132];    // conv3 out (128 ch), padded
  __shared__ float xi_s[Kk][2];
  __shared__ float loa_s[Kk][2];
  __shared__ float u_s[Kk][2];

  const int blk = blockIdx.x;
  const int b = blk >> 10;           // S == 1024
  const int s = blk & (Ss - 1);
  const int t = threadIdx.x;

  // new_idx = np.linspace(0, N-1, S).astype(int64): identical IEEE ops, endpoint exact
  int ci;
  if (s == Ss - 1) {
    ci = Nn - 1;
  } else {
    ci = (int)(long long)((double)s * (8191.0 / 1023.0));
  }

  // ---- gather prev features into cat[:, 64..127] (independent of feature phase) ----
  {
#pragma unroll
    for (int i = 0; i < 8; ++i) {
      int e = t + 256 * i;        // 0..2047
      int c = e >> 5;             // 0..63
      int k = e & 31;             // 0..31
      int n = (ci - (Kk / 2) + k + Nn) & (Nn - 1);
      cat[k][64 + c] = prev[(b * 64 + c) * Nn + n];
    }
  }

  // ---- feature phase 1: points, f4/u/a1/a2/f3o ----
  if (t < Kk) {
    int n = (ci - (Kk / 2) + t + Nn) & (Nn - 1);
    float xix = contour[(b * Nn + n) * 2 + 0];
    float xiy = contour[(b * Nn + n) * 2 + 1];
    float lx  = loa[(b * Nn + n) * 2 + 0];
    float ly  = loa[(b * Nn + n) * 2 + 1];
    xi_s[t][0] = xix; xi_s[t][1] = xiy;
    loa_s[t][0] = lx; loa_s[t][1] = ly;

    float sx  = contour[(b * Nn + ci) * 2 + 0];
    float sy  = contour[(b * Nn + ci) * 2 + 1];
    float lcx = loa[(b * Nn + ci) * 2 + 0];
    float lcy = loa[(b * Nn + ci) * 2 + 1];

    float vx = xix - sx, vy = xiy - sy;
    float f4 = sqrtf(vx * vx + vy * vy);
    float inv = 1.0f / (f4 + F_EPS);
    float ux = vx * inv, uy = vy * inv;
    u_s[t][0] = ux; u_s[t][1] = uy;

    float a1 = lcx * ux + lcy * uy;
    float a2 = -(lx * ux + ly * uy);
    float dotp = lx * lcx + ly * lcy;
    float cl = fminf(fmaxf(dotp, -1.0f + F_EPS), 1.0f - F_EPS);
    float ang = acosf(cl);
    float f3o = (a1 < a2 ? 1.0f : -1.0f) * ang;

    rif[t][0] = f4;
    rif[t][2] = a1;
    rif[t][3] = a2;
    rif[t][4] = f3o;
  }
  __syncthreads();

  // ---- feature phase 2: rolled features d2/a4/a5/f7o ----
  if (t < Kk) {
    float pxx = 0.f, pxy = 0.f, plx = 0.f, ply = 0.f, pux = 0.f, puy = 0.f;
    if (t > 0) {
      pxx = xi_s[t - 1][0]; pxy = xi_s[t - 1][1];
      plx = loa_s[t - 1][0]; ply = loa_s[t - 1][1];
      pux = u_s[t - 1][0];  puy = u_s[t - 1][1];
    }
    float lx = loa_s[t][0], ly = loa_s[t][1];
    float vpx = (t > 0) ? (xi_s[t][0] - pxx) : 0.0f;
    float vpy = (t > 0) ? (xi_s[t][1] - pxy) : 0.0f;
    float f8 = sqrtf(vpx * vpx + vpy * vpy);
    float inv = 1.0f / (f8 + F_EPS);
    float upx = vpx * inv, upy = vpy * inv;

    float a4 = upx * lx + upy * ly;
    float a5 = upx * plx + upy * ply;
    float dotp = lx * plx + ly * ply;
    float cl = fminf(fmaxf(dotp, -1.0f + F_EPS), 1.0f - F_EPS);
    float ang = acosf(cl);
    float f7o = (a4 < a5 ? 1.0f : -1.0f) * ang;

    float du = u_s[t][0] * pux + u_s[t][1] * puy;
    float cl2 = fminf(fmaxf(du, -1.0f + F_EPS), 1.0f - F_EPS);
    float d2 = acosf(cl2);

    rif[t][1] = d2;
    rif[t][5] = a4;
    rif[t][6] = a5;
    rif[t][7] = f7o;
  }
  __syncthreads();

  // ---- conv1: 8 -> 32 ----
  {
#pragma unroll
    for (int i = 0; i < 4; ++i) {
      int e = t + 256 * i;       // 0..1023
      int k = e >> 5;
      int o = e & 31;
      const float4 w0 = *(const float4*)(ew1 + o * 8);
      const float4 w1 = *(const float4*)(ew1 + o * 8 + 4);
      const float4 r0 = *(const float4*)(&rif[k][0]);
      const float4 r1 = *(const float4*)(&rif[k][4]);
      float acc = w0.x * r0.x + w0.y * r0.y + w0.z * r0.z + w0.w * r0.w
                + w1.x * r1.x + w1.y * r1.y + w1.z * r1.z + w1.w * r1.w;
      float scale = eg1[o] * rsqrtf(ev1[o] + F_BN_EPS);
      float y = (acc + eb1[o] - em1[o]) * scale + ebeta1[o];
      h1[k][o] = fmaxf(y, 0.0f);
    }
  }
  __syncthreads();

  // ---- conv2: 32 -> 64, into cat[:, 0..63] ----
  {
#pragma unroll
    for (int i = 0; i < 8; ++i) {
      int e = t + 256 * i;       // 0..2047
      int k = e >> 6;
      int o = e & 63;
      const float4* wr = (const float4*)(ew2 + o * 32);
      float acc = 0.f;
#pragma unroll
      for (int c4 = 0; c4 < 8; ++c4) {
        float4 w = wr[c4];
        float4 h = *(const float4*)(&h1[k][c4 * 4]);
        acc += w.x * h.x + w.y * h.y + w.z * h.z + w.w * h.w;
      }
      float scale = eg2[o] * rsqrtf(ev2[o] + F_BN_EPS);
      float y = (acc + eb2[o] - em2[o]) * scale + ebeta2[o];
      cat[k][o] = fmaxf(y, 0.0f);
    }
  }
  __syncthreads();

  // ---- conv3: 128 -> 128 ----
  {
    const int o = t & 127;
    const int kh = (t >> 7) << 4;   // 0 or 16
    const float4* wr = (const float4*)(fw1 + o * 128);
    float acc[16];
#pragma unroll
    for (int j = 0; j < 16; ++j) acc[j] = 0.f;
    for (int c4 = 0; c4 < 32; ++c4) {
      float4 w = wr[c4];
#pragma unroll
      for (int j = 0; j < 16; ++j) {
        float4 h = *(const float4*)(&cat[kh + j][c4 * 4]);
        acc[j] += w.x * h.x + w.y * h.y + w.z * h.z + w.w * h.w;
      }
    }
    float scale = fg1[o] * rsqrtf(fv1[o] + F_BN_EPS);
    float bb = fb1[o], mm = fm1[o], bt = fbeta1[o];
#pragma unroll
    for (int j = 0; j < 16; ++j) {
      float y = (acc[j] + bb - mm) * scale + bt;
      h3[kh + j][o] = fmaxf(y, 0.0f);
    }
  }
  __syncthreads();

  // ---- conv4: 128 -> 256, fused max over k, write out ----
  {
    const int o = t;   // 0..255
    const float4* wr = (const float4*)(fw2 + o * 128);
    float acc[32];
#pragma unroll
    for (int k = 0; k < 32; ++k) acc[k] = 0.f;
    for (int c4 = 0; c4 < 32; ++c4) {
      float4 w = wr[c4];
#pragma unroll
      for (int k = 0; k < 32; ++k) {
        float4 h = *(const float4*)(&h3[k][c4 * 4]);
        acc[k] += w.x * h.x + w.y * h.y + w.z * h.z + w.w * h.w;
      }
    }
    float scale = fg2[o] * rsqrtf(fv2[o] + F_BN_EPS);
    float bb = fb2[o], mm = fm2[o], bt = fbeta2[o];
    float mx = -INFINITY;
#pragma unroll
    for (int k = 0; k < 32; ++k) {
      float y = (acc[k] + bb - mm) * scale + bt;
      y = fmaxf(y, 0.0f);
      mx = fmaxf(mx, y);
    }
    out[(b * 256 + o) * Ss + s] = mx;
  }
}

}  // namespace

extern "C" void kernel_launch(void* const* d_in, const int* in_sizes, int n_in,
                              void* d_out, int out_size, void* d_ws, size_t ws_size,
                              hipStream_t stream) {
  (void)in_sizes; (void)n_in; (void)d_ws; (void)ws_size; (void)out_size;

  const float* contour = (const float*)d_in[0];
  const float* loa     = (const float*)d_in[1];
  const float* prev    = (const float*)d_in[2];
  const float* ew1 = (const float*)d_in[3];
  const float* eb1 = (const float*)d_in[4];
  const float* eg1 = (const float*)d_in[5];
  const float* ebeta1 = (const float*)d_in[6];
  const float* em1 = (const float*)d_in[7];
  const float* ev1 = (const float*)d_in[8];
  const float* ew2 = (const float*)d_in[9];
  const float* eb2 = (const float*)d_in[10];
  const float* eg2 = (const float*)d_in[11];
  const float* ebeta2 = (const float*)d_in[12];
  const float* em2 = (const float*)d_in[13];
  const float* ev2 = (const float*)d_in[14];
  const float* fw1 = (const float*)d_in[15];
  const float* fb1 = (const float*)d_in[16];
  const float* fg1 = (const float*)d_in[17];
  const float* fbeta1 = (const float*)d_in[18];
  const float* fm1 = (const float*)d_in[19];
  const float* fv1 = (const float*)d_in[20];
  const float* fw2 = (const float*)d_in[21];
  const float* fb2 = (const float*)d_in[22];
  const float* fg2 = (const float*)d_in[23];
  const float* fbeta2 = (const float*)d_in[24];
  const float* fm2 = (const float*)d_in[25];
  const float* fv2 = (const float*)d_in[26];

  float* out = (float*)d_out;

  rcri_fused<<<dim3(8 * Ss), dim3(256), 0, stream>>>(
      contour, loa, prev,
      ew1, eb1, eg1, ebeta1, em1, ev1,
      ew2, eb2, eg2, ebeta2, em2, ev2,
      fw1, fb1, fg1, fbeta1, fm1, fv1,
      fw2, fb2, fg2, fbeta2, fm2, fv2,
      out);
}